// Round 5
// baseline (162.215 us; speedup 1.0000x reference)
//
#include <hip/hip_runtime.h>
#include <hip/hip_bf16.h>

typedef __bf16 bf16x8 __attribute__((ext_vector_type(8)));
typedef float f32x16 __attribute__((ext_vector_type(16)));

typedef __attribute__((address_space(1))) void GAS;
typedef __attribute__((address_space(3))) void LAS;
#define GLOAD16(gp, lp) __builtin_amdgcn_global_load_lds((GAS*)(gp), (LAS*)(lp), 16, 0, 0)

#define NB 4096
#define NDU 1024  // concat [hi | lo] width
#define NKT 16    // 1024 / 64

// ---------------- Kernel 1: row-normalize + split into u = [hi | lo]; zero stats ----------------
__global__ __launch_bounds__(256) void nrm_split_k(const float* __restrict__ x,
                                                   __bf16* __restrict__ u,
                                                   float* __restrict__ stats) {
    if (blockIdx.x == 0 && threadIdx.x < 21) stats[threadIdx.x] = 0.0f;  // 20 stats + ticket
    const int wid = threadIdx.x >> 6, lane = threadIdx.x & 63;
    const int row = blockIdx.x * 4 + wid;
    const float4* xr = reinterpret_cast<const float4*>(x + (size_t)row * 512);
    float4 v0 = xr[lane * 2 + 0];
    float4 v1 = xr[lane * 2 + 1];
    float xv[8] = {v0.x, v0.y, v0.z, v0.w, v1.x, v1.y, v1.z, v1.w};
    float ss = 0.0f;
#pragma unroll
    for (int j = 0; j < 8; ++j) ss += xv[j] * xv[j];
#pragma unroll
    for (int off = 32; off > 0; off >>= 1) ss += __shfl_xor(ss, off);
    const float rn = 1.0f / fmaxf(sqrtf(ss), 1e-12f);
    bf16x8 h, l;
#pragma unroll
    for (int j = 0; j < 8; ++j) {
        float xn = xv[j] * rn;
        __bf16 hb = (__bf16)xn;
        h[j] = hb;
        l[j] = (__bf16)(xn - (float)hb);  // xn == hi + lo to ~2^-17
    }
    reinterpret_cast<bf16x8*>(u + (size_t)row * NDU)[lane] = h;
    reinterpret_cast<bf16x8*>(u + (size_t)row * NDU + 512)[lane] = l;
}

// ------- Kernel 2: 256^2-tile GEMM cos = u u^T (K=1024), 2-phase loop, fused histogram+finalize -------
__global__ __launch_bounds__(512, 2) void gemm_stat_k(const __bf16* __restrict__ u,
                                                      const int* __restrict__ targets,
                                                      const float* __restrict__ acc_sum,
                                                      float* __restrict__ stats,
                                                      float* __restrict__ out) {
    // [slot][half: 0=A0 1=A1 2=B0 3=B1][128 rows x 64 cols bf16], XOR-swizzled 16B granule
    __shared__ __align__(16) __bf16 lds[2][4][128 * 64];
    __shared__ int tgtR[256], tgtC[256];
    __shared__ float red_s[8][10], red_c[8][10];

    const int bid = blockIdx.x;
    const int swz = (bid & 7) * 32 + (bid >> 3);  // 256 blocks, 8 XCDs, bijective
    const int by = swz >> 4, bx = swz & 15;
    const int row0 = by * 256, col0 = bx * 256;
    const int tid = threadIdx.x, lane = tid & 63;
    const int wid = tid >> 6, wr = wid >> 2, wc = wid & 3;  // 2 x 4 waves

    if (tid < 256) tgtR[tid] = targets[row0 + tid];
    else           tgtC[tid - 256] = targets[col0 + tid - 256];

    // staging: half-tile = 128x64 bf16 = 1024 x 16B chunks; thread owns chunks tid (rows 0-63)
    // and tid+512 (rows 64-127). XOR term x0 is invariant across halves/chunks (row deltas % 8 == 0).
    const int r0c = tid >> 3;
    const int x0 = ((tid & 7) ^ (r0c & 7)) * 8;
    const __bf16* A0 = u + (size_t)(row0 + r0c) * NDU + x0;
    const __bf16* B0 = u + (size_t)(col0 + r0c) * NDU + x0;
    const int de0 = tid * 8, de1 = tid * 8 + 4096;  // LDS element dests (linear)

    auto STAGE = [&](int kt) {
        const int slot = kt & 1, kc = kt * 64;
        GLOAD16(A0 + kc,             &lds[slot][0][de0]);
        GLOAD16(A0 + kc +  64 * NDU, &lds[slot][0][de1]);
        GLOAD16(A0 + kc + 128 * NDU, &lds[slot][1][de0]);
        GLOAD16(A0 + kc + 192 * NDU, &lds[slot][1][de1]);
        GLOAD16(B0 + kc,             &lds[slot][2][de0]);
        GLOAD16(B0 + kc +  64 * NDU, &lds[slot][2][de1]);
        GLOAD16(B0 + kc + 128 * NDU, &lds[slot][3][de0]);
        GLOAD16(B0 + kc + 192 * NDU, &lds[slot][3][de1]);
    };

    // fragment read offsets (32x32x16); row&7 == lane&7 for all fragment rows
    const int l31 = lane & 31, hi2 = lane >> 5;
    const int xr_ = (lane & 7) << 3;
    int rowAe[4], rowBe[2];
#pragma unroll
    for (int m = 0; m < 4; ++m) rowAe[m] = (m * 32 + l31) * 64;
#pragma unroll
    for (int n = 0; n < 2; ++n) rowBe[n] = ((wc & 1) * 64 + n * 32 + l31) * 64;

    const f32x16 fz = {0,0,0,0, 0,0,0,0, 0,0,0,0, 0,0,0,0};
    f32x16 acc[4][2];
#pragma unroll
    for (int m = 0; m < 4; ++m)
#pragma unroll
        for (int n = 0; n < 2; ++n) acc[m][n] = fz;

    // prologue: tile 0 resident
    STAGE(0);
    asm volatile("s_waitcnt vmcnt(0)" ::: "memory");
    __builtin_amdgcn_s_barrier();

    for (int kt = 0; kt < NKT; ++kt) {
        if (kt + 1 < NKT) STAGE(kt + 1);  // into slot^1 (free: last read pre-barrier at kt-1)
        const int slot = kt & 1;
        const __bf16* lA = &lds[slot][wr][0];
        const __bf16* lB = &lds[slot][2 + (wc >> 1)][0];
#pragma unroll
        for (int ks = 0; ks < 4; ++ks) {  // one k-step: fragments live only here (24 VGPRs)
            const int ce = (ks * 16 + hi2 * 8) ^ xr_;
            bf16x8 af[4], bf[2];
#pragma unroll
            for (int m = 0; m < 4; ++m)
                af[m] = *reinterpret_cast<const bf16x8*>(lA + rowAe[m] + ce);
#pragma unroll
            for (int n = 0; n < 2; ++n)
                bf[n] = *reinterpret_cast<const bf16x8*>(lB + rowBe[n] + ce);
#pragma unroll
            for (int m = 0; m < 4; ++m)
#pragma unroll
                for (int n = 0; n < 2; ++n)
                    acc[m][n] = __builtin_amdgcn_mfma_f32_32x32x16_bf16(
                        af[m], bf[n], acc[m][n], 0, 0, 0);
        }
        asm volatile("s_waitcnt vmcnt(0)" ::: "memory");  // next tile landed (issued a body ago)
        __builtin_amdgcn_s_barrier();
    }

    // ---- epilogue: per-lane histogram of g=|cos-label| over 128 elements ----
    // 32x32 C/D layout: col = lane&31, row = (reg&3) + 8*(reg>>2) + 4*(lane>>5)
    int tcv[2];
#pragma unroll
    for (int n = 0; n < 2; ++n) tcv[n] = tgtC[wc * 64 + n * 32 + l31];

    constexpr float E[11] = {0.0f, 0.1f, 0.2f, 0.3f, 0.4f, 0.5f,
                             0.6f, 0.7f, 0.8f, 0.9f, 1.0f + 1e-6f};
    float sacc[10], cacc[10];
#pragma unroll
    for (int b = 0; b < 10; ++b) { sacc[b] = 0.0f; cacc[b] = 0.0f; }

#pragma unroll
    for (int m = 0; m < 4; ++m) {
        const int rbase = wr * 128 + m * 32 + hi2 * 4;
        int trv[16];
#pragma unroll
        for (int reg = 0; reg < 16; ++reg)
            trv[reg] = tgtR[rbase + (reg >> 2) * 8 + (reg & 3)];
#pragma unroll
        for (int n = 0; n < 2; ++n) {
            f32x16 v = acc[m][n];
            const int tc = tcv[n];
#pragma unroll
            for (int reg = 0; reg < 16; ++reg) {
                const float label = (trv[reg] == tc) ? 1.0f : 0.0f;
                const float g = fabsf(v[reg] - label);
                const float g2 = g * g;
                bool prev = true;
#pragma unroll
                for (int b = 0; b < 10; ++b) {
                    const bool ge = (g >= E[b + 1]);
                    const bool in = prev && (!ge);
                    sacc[b] += in ? g2 : 0.0f;
                    cacc[b] += in ? 1.0f : 0.0f;
                    prev = ge;
                }
            }
        }
    }

#pragma unroll
    for (int b = 0; b < 10; ++b) {
        float sv = sacc[b], cv = cacc[b];
#pragma unroll
        for (int off = 32; off > 0; off >>= 1) {
            sv += __shfl_xor(sv, off);
            cv += __shfl_xor(cv, off);
        }
        if (lane == 0) { red_s[wid][b] = sv; red_c[wid][b] = cv; }
    }
    __syncthreads();
    if (tid < 10) {
        float s = 0.0f, c = 0.0f;
#pragma unroll
        for (int w = 0; w < 8; ++w) { s += red_s[w][tid]; c += red_c[w][tid]; }
        atomicAdd(&stats[tid], s);
        atomicAdd(&stats[10 + tid], c);
        __threadfence();
    }
    __syncthreads();

    // ---- fused finalize: last block computes the loss ----
    if (tid == 0) {
        int old = atomicAdd((int*)&stats[20], 1);
        if (old == 255) {
            __threadfence();
            const float tot = 16777216.0f;  // 4096^2
            double num = 0.0, valid = 0.0;
#pragma unroll
            for (int b = 0; b < 10; ++b) {
                float sb = atomicAdd(&stats[b], 0.0f);
                float cnt = atomicAdd(&stats[10 + b], 0.0f);
                float accn = 0.5f * acc_sum[b] + 0.5f * cnt;
                float w = tot / (accn + 1e-6f);
                num += (double)sb * (double)w;
                valid += (double)cnt;
            }
            out[0] = (valid > 0.0) ? (float)(num / valid / 16777216.0) : 0.0f;
        }
    }
}

extern "C" void kernel_launch(void* const* d_in, const int* in_sizes, int n_in,
                              void* d_out, int out_size, void* d_ws, size_t ws_size,
                              hipStream_t stream) {
    const float* x = (const float*)d_in[0];
    const float* acc_sum = (const float*)d_in[1];
    const int* targets = (const int*)d_in[2];
    float* out = (float*)d_out;

    char* ws = (char*)d_ws;
    __bf16* u = (__bf16*)ws;                                          // 4096 x 1024 bf16 = 8 MB
    float* stats = (float*)(ws + (size_t)NB * NDU * sizeof(__bf16));  // 20 stats + ticket

    nrm_split_k<<<NB / 4, 256, 0, stream>>>(x, u, stats);
    gemm_stat_k<<<256, 512, 0, stream>>>(u, targets, acc_sum, stats, out);
}

// Round 6
// 157.903 us; speedup vs baseline: 1.0273x; 1.0273x over previous
//
#include <hip/hip_runtime.h>
#include <hip/hip_bf16.h>

typedef __bf16 bf16x8 __attribute__((ext_vector_type(8)));
typedef float f32x4 __attribute__((ext_vector_type(4)));

typedef __attribute__((address_space(1))) void GAS;
typedef __attribute__((address_space(3))) void LAS;
#define GLOAD16(gp, lp) __builtin_amdgcn_global_load_lds((GAS*)(gp), (LAS*)(lp), 16, 0, 0)

#define NB 4096
#define NDU 1024  // concat [hi | lo] width
#define NKT 16    // 1024 / 64
#define NBLK 256

// ---------------- Kernel 1: row-normalize + split into u = [hi | lo]; zero part/ticket ----------------
__global__ __launch_bounds__(256) void nrm_split_k(const float* __restrict__ x,
                                                   __bf16* __restrict__ u,
                                                   float* __restrict__ part,
                                                   int* __restrict__ ticket) {
    if (blockIdx.x < 20) part[blockIdx.x * NBLK + threadIdx.x] = 0.0f;  // 20 x 256 partials
    if (blockIdx.x == 20 && threadIdx.x == 0) *ticket = 0;
    const int wid = threadIdx.x >> 6, lane = threadIdx.x & 63;
    const int row = blockIdx.x * 4 + wid;
    const float4* xr = reinterpret_cast<const float4*>(x + (size_t)row * 512);
    float4 v0 = xr[lane * 2 + 0];
    float4 v1 = xr[lane * 2 + 1];
    float xv[8] = {v0.x, v0.y, v0.z, v0.w, v1.x, v1.y, v1.z, v1.w};
    float ss = 0.0f;
#pragma unroll
    for (int j = 0; j < 8; ++j) ss += xv[j] * xv[j];
#pragma unroll
    for (int off = 32; off > 0; off >>= 1) ss += __shfl_xor(ss, off);
    const float rn = 1.0f / fmaxf(sqrtf(ss), 1e-12f);
    bf16x8 h, l;
#pragma unroll
    for (int j = 0; j < 8; ++j) {
        float xn = xv[j] * rn;
        __bf16 hb = (__bf16)xn;
        h[j] = hb;
        l[j] = (__bf16)(xn - (float)hb);  // xn == hi + lo to ~2^-17
    }
    reinterpret_cast<bf16x8*>(u + (size_t)row * NDU)[lane] = h;
    reinterpret_cast<bf16x8*>(u + (size_t)row * NDU + 512)[lane] = l;
}

// ------- Kernel 2: r2-core 256^2 8-phase GEMM (K=1024) + histogram + contention-free finalize -------
__global__ __launch_bounds__(512, 2) void gemm_stat_k(const __bf16* __restrict__ u,
                                                      const int* __restrict__ targets,
                                                      const float* __restrict__ acc_sum,
                                                      float* __restrict__ part,
                                                      int* __restrict__ ticket,
                                                      float* __restrict__ out) {
    // [slot][A=0/B=1][half][128 rows x 64 cols], rows 128B, XOR-swizzled storage (r2 verbatim)
    __shared__ __align__(16) __bf16 lds[2][2][2][128 * 64];
    __shared__ int tgtR[256], tgtC[256];
    __shared__ float red_s[8][10], red_c[8][10];
    __shared__ float tot[20];
    __shared__ int is_last;

    const int bid = blockIdx.x;
    const int swz = (bid & 7) * 32 + (bid >> 3);  // 256 blocks, 8 XCDs, bijective
    const int by = swz >> 4, bx = swz & 15;
    const int row0 = by * 256, col0 = bx * 256;
    const int tid = threadIdx.x, lane = tid & 63;
    const int wid = tid >> 6, wr = wid >> 2, wc = wid & 3;  // 2 x 4 waves

    if (tid < 256) tgtR[tid] = targets[row0 + tid];
    else           tgtC[tid - 256] = targets[col0 + tid - 256];

    // staging: half-tile = 128x64 bf16 = 1024 x 16B chunks; thread handles chunks tid, tid+512
    const int c0 = tid, c1 = tid + 512;
    const int r0c = c0 >> 3, x0 = ((c0 & 7) ^ (r0c & 7)) * 8;  // inverse-swizzled source col
    const int r1c = c1 >> 3, x1 = ((c1 & 7) ^ (r1c & 7)) * 8;

    auto STAGE = [&](int s) {  // s = half-tile stream position, 0..63
        const int kt = s >> 2, h4 = s & 3;  // h4: 0,1 = A-half; 2,3 = B-half
        const int slot = kt & 1, kcol = kt * 64;
        const bool isA = (h4 < 2);
        const int half = h4 & 1;
        const int brow = (isA ? row0 : col0) + half * 128;
        __bf16* ldst = &lds[slot][isA ? 0 : 1][half][0];
        GLOAD16(u + (size_t)(brow + r0c) * NDU + kcol + x0, ldst + c0 * 8);
        GLOAD16(u + (size_t)(brow + r1c) * NDU + kcol + x1, ldst + c1 * 8);
    };

    const f32x4 fzero = {0.0f, 0.0f, 0.0f, 0.0f};
    f32x4 acc[8][4];
#pragma unroll
    for (int a = 0; a < 8; ++a)
#pragma unroll
        for (int n = 0; n < 4; ++n) acc[a][n] = fzero;

    // prologue: kt0's 4 half-tiles + kt1.A0 in flight
    STAGE(0); STAGE(1); STAGE(2); STAGE(3); STAGE(4);
    asm volatile("s_waitcnt vmcnt(2)" ::: "memory");  // kt0 fully resident
    __builtin_amdgcn_s_barrier();
    __builtin_amdgcn_sched_barrier(0);

    const int fr = lane & 15, hi16 = lane >> 4;
    const int Bhalf = wc >> 1;

    for (int kt = 0; kt < NKT; ++kt) {
        const int slot = kt & 1;
        const __bf16* lA = &lds[slot][0][0][0];
        const __bf16* lB = &lds[slot][1][Bhalf][0];
#pragma unroll
        for (int f = 0; f < 4; ++f) {  // quadrant phase: (Mhalf, khalf)
            const int Mh = f >> 1, kh = f & 1;
            bf16x8 af[4], bf[4];
#pragma unroll
            for (int q = 0; q < 4; ++q) {
                const int row = wr * 64 + q * 16 + fr;
                const int cb = (kh * 64 + hi16 * 16) ^ ((row & 7) << 4);
                af[q] = *(const bf16x8*)((const char*)(lA + Mh * 8192) + row * 128 + cb);
            }
#pragma unroll
            for (int n = 0; n < 4; ++n) {
                const int row = (wc & 1) * 64 + n * 16 + fr;
                const int cb = (kh * 64 + hi16 * 16) ^ ((row & 7) << 4);
                bf[n] = *(const bf16x8*)((const char*)lB + row * 128 + cb);
            }
            const int s = 4 * kt + f + 5;  // issue 5 half-tiles ahead
            if (s < 4 * NKT) STAGE(s);
            __builtin_amdgcn_s_barrier();  // B1
            __builtin_amdgcn_sched_barrier(0);
            __builtin_amdgcn_s_setprio(1);
#pragma unroll
            for (int q = 0; q < 4; ++q)
#pragma unroll
                for (int n = 0; n < 4; ++n)
                    acc[Mh * 4 + q][n] = __builtin_amdgcn_mfma_f32_16x16x32_bf16(
                        af[q], bf[n], acc[Mh * 4 + q][n], 0, 0, 0);
            __builtin_amdgcn_s_setprio(0);
            __builtin_amdgcn_sched_barrier(0);
            if (f == 3) {  // K-tile boundary: next tile's halves must be resident
                if (kt < NKT - 2)       asm volatile("s_waitcnt vmcnt(2)" ::: "memory");
                else if (kt == NKT - 2) asm volatile("s_waitcnt vmcnt(0)" ::: "memory");
            }
            __builtin_amdgcn_s_barrier();  // B2
            __builtin_amdgcn_sched_barrier(0);
        }
    }

    // ---- epilogue: per-lane histogram of g=|cos-label| over 128 elements (r2 verbatim) ----
    int tcv[4];
#pragma unroll
    for (int n = 0; n < 4; ++n) tcv[n] = tgtC[wc * 64 + n * 16 + fr];

    constexpr float E[11] = {0.0f, 0.1f, 0.2f, 0.3f, 0.4f, 0.5f,
                             0.6f, 0.7f, 0.8f, 0.9f, 1.0f + 1e-6f};
    float sacc[10], cacc[10];
#pragma unroll
    for (int b = 0; b < 10; ++b) { sacc[b] = 0.0f; cacc[b] = 0.0f; }

    const int rB = wr * 64 + hi16 * 4;
#pragma unroll
    for (int a = 0; a < 8; ++a) {
        int trv[4];
#pragma unroll
        for (int r = 0; r < 4; ++r) trv[r] = tgtR[(a >> 2) * 128 + rB + (a & 3) * 16 + r];
#pragma unroll
        for (int n = 0; n < 4; ++n) {
            f32x4 v = acc[a][n];
            const int tc = tcv[n];
#pragma unroll
            for (int r = 0; r < 4; ++r) {
                const float label = (trv[r] == tc) ? 1.0f : 0.0f;
                const float g = fabsf(v[r] - label);
                const float g2 = g * g;
                bool prev = true;
#pragma unroll
                for (int b = 0; b < 10; ++b) {
                    const bool ge = (g >= E[b + 1]);
                    const bool in = prev && (!ge);
                    sacc[b] += in ? g2 : 0.0f;
                    cacc[b] += in ? 1.0f : 0.0f;
                    prev = ge;
                }
            }
        }
    }

#pragma unroll
    for (int b = 0; b < 10; ++b) {
        float sv = sacc[b], cv = cacc[b];
#pragma unroll
        for (int off = 32; off > 0; off >>= 1) {
            sv += __shfl_xor(sv, off);
            cv += __shfl_xor(cv, off);
        }
        if (lane == 0) { red_s[wid][b] = sv; red_c[wid][b] = cv; }
    }
    __syncthreads();

    // ---- contention-free partials: device-scope stores to DISTINCT slots ----
    if (tid < 10) {
        float s = 0.0f, c = 0.0f;
#pragma unroll
        for (int w = 0; w < 8; ++w) { s += red_s[w][tid]; c += red_c[w][tid]; }
        __hip_atomic_store(&part[tid * NBLK + bid], s,
                           __ATOMIC_RELAXED, __HIP_MEMORY_SCOPE_AGENT);
        __hip_atomic_store(&part[(10 + tid) * NBLK + bid], c,
                           __ATOMIC_RELAXED, __HIP_MEMORY_SCOPE_AGENT);
    }
    __syncthreads();  // drains each wave's vmcnt -> stores at coherence point

    if (tid == 0) {
        int old = __hip_atomic_fetch_add(ticket, 1, __ATOMIC_ACQ_REL,
                                         __HIP_MEMORY_SCOPE_AGENT);
        is_last = (old == NBLK - 1) ? 1 : 0;
    }
    __syncthreads();

    // ---- last block: parallel-reduce the 20x256 partials, compute loss ----
    if (is_last) {
        for (int b = wid; b < 20; b += 8) {
            float v = 0.0f;
#pragma unroll
            for (int j = 0; j < 4; ++j)
                v += __hip_atomic_load(&part[b * NBLK + lane + 64 * j],
                                       __ATOMIC_RELAXED, __HIP_MEMORY_SCOPE_AGENT);
#pragma unroll
            for (int off = 32; off > 0; off >>= 1) v += __shfl_xor(v, off);
            if (lane == 0) tot[b] = v;
        }
        __syncthreads();
        if (tid == 0) {
            const float totN = 16777216.0f;  // 4096^2
            double num = 0.0, valid = 0.0;
#pragma unroll
            for (int b = 0; b < 10; ++b) {
                float cnt = tot[10 + b];
                float accn = 0.5f * acc_sum[b] + 0.5f * cnt;
                float w = totN / (accn + 1e-6f);
                num += (double)tot[b] * (double)w;
                valid += (double)cnt;
            }
            out[0] = (valid > 0.0) ? (float)(num / valid / 16777216.0) : 0.0f;
        }
    }
}

extern "C" void kernel_launch(void* const* d_in, const int* in_sizes, int n_in,
                              void* d_out, int out_size, void* d_ws, size_t ws_size,
                              hipStream_t stream) {
    const float* x = (const float*)d_in[0];
    const float* acc_sum = (const float*)d_in[1];
    const int* targets = (const int*)d_in[2];
    float* out = (float*)d_out;

    char* ws = (char*)d_ws;
    __bf16* u = (__bf16*)ws;                                   // 4096 x 1024 bf16 = 8 MB
    float* part = (float*)(ws + (size_t)NB * NDU * sizeof(__bf16));  // 20 x 256 partials
    int* ticket = (int*)(part + 20 * NBLK);

    nrm_split_k<<<NB / 4, 256, 0, stream>>>(x, u, part, ticket);
    gemm_stat_k<<<NBLK, 512, 0, stream>>>(u, targets, acc_sum, part, ticket, out);
}